// Round 2
// baseline (254.564 us; speedup 1.0000x reference)
//
#include <hip/hip_runtime.h>
#include <hip/hip_bf16.h>
#include <stdint.h>

// y = x @ W^T + bias ; x:(32,4096) f32, W:(11008,4096) f32, bias:(11008) f32
//
// HBM-latency analysis: W (180 MB) must stream once; the VGPR-load version kept
// only ~128 B/wave in flight -> 0.72 TB/s (latency-bound; Little's law:
// 2752 waves * 128 B / 375 ns). This version streams W through LDS with async
// global_load_lds (1 KB in flight per instruction, no VGPR cost):
//   - per wave: private K-slice of 1024, 8 chunks of 128 k (8 KB each),
//     double-buffered LDS ring, counted s_waitcnt vmcnt(16) (never 0 mid-loop)
//   - no barriers in the K-loop (buffers are per-wave; waves free-run)
//   - A-frags register-double-buffered per chunk, issued with the W stage so
//     the in-order vmcnt arithmetic stays exact: 16 vmem ops per iteration,
//     vmcnt(16) == "chunk c's W and A landed"
//   - T2 bank-conflict swizzle, both-sides (rule #21): LDS linear for the DMA,
//     global source pre-swizzled by (slot ^ (row&7)) in 16B granules, ds_read
//     applies the same XOR. 512B row stride would otherwise be 16-way.
// In flight per CU at 2 blocks/CU: 8 waves * 8 KB = 64 KB >> ~12 KB needed
// for 6.3 TB/s at ~900 cy latency.

#define M 32
#define N 11008
#define K 4096
#define BN 16
#define WKSLICE (K / 4)           // 1024 k per wave
#define CK 128                    // k floats per chunk per wave
#define NCHUNK (WKSLICE / CK)     // 8 chunks
#define CHFL (16 * CK)            // floats per chunk buffer (2048 = 8 KB)

typedef __attribute__((ext_vector_type(8))) short bf16x8;
typedef __attribute__((ext_vector_type(4))) float f32x4;
typedef unsigned int u32;

// two fp32 -> packed bf16 pair, round-to-nearest-even (finite inputs)
static __device__ __forceinline__ u32 pk2bf(float f0, float f1) {
    u32 u0 = __float_as_uint(f0);
    u32 u1 = __float_as_uint(f1);
    u0 += 0x7fffu + ((u0 >> 16) & 1u);
    u1 += 0x7fffu + ((u1 >> 16) & 1u);
    return (u0 >> 16) | (u1 & 0xffff0000u);
}

// async 16B-per-lane global->LDS copy; lds dest is wave-uniform base,
// HW writes lane l at base + l*16.
static __device__ __forceinline__ void async_cp16(const float* g, float* l) {
    __builtin_amdgcn_global_load_lds(
        (const __attribute__((address_space(1))) u32*)g,
        (__attribute__((address_space(3))) u32*)l, 16, 0, 0);
}

// ---------------------------------------------------------------------------
// Kernel 1: x fp32 -> bf16 (unchanged from passing version)
// ---------------------------------------------------------------------------
__global__ __launch_bounds__(256) void cvt_kernel(
    const float* __restrict__ x, unsigned short* __restrict__ xbf)
{
    int i = blockIdx.x * 256 + threadIdx.x;          // 128 blocks x 256 = 32768
    f32x4 v = ((const f32x4*)x)[i];
    uint2 o;
    o.x = pk2bf(v.x, v.y);
    o.y = pk2bf(v.z, v.w);
    ((uint2*)xbf)[i] = o;
}

// ---------------------------------------------------------------------------
// Kernel 2: GEMM, wave-autonomous K-streaming through async LDS ring.
// Fragment mapping identical to the verified version:
//   B-frag: lane holds B[k = quad*8 + j][n = l15] = W[nbase+l15][k]
//   A-frag: lane holds A[m = l15 (+16)][k = quad*8 + j]
//   C/D:    col = lane&15, row = quad*4 + reg
// ---------------------------------------------------------------------------
__global__ __launch_bounds__(256) void gemm_kernel(
    const float* __restrict__ W, const unsigned short* __restrict__ xbf,
    const float* __restrict__ bias, float* __restrict__ out)
{
    __shared__ float wbuf[4 * 2 * CHFL];   // 4 waves x 2 bufs x 8 KB = 64 KB
    __shared__ float red[4 * 512];         // 8 KB cross-wave reduction

    const int tid  = threadIdx.x;
    const int wave = tid >> 6;
    const int lane = tid & 63;
    const int quad = lane >> 4;
    const int l15  = lane & 15;
    const int rp   = lane >> 5;     // staging: row within pair
    const int slot = lane & 31;     // staging: 16B slot within 512B row
    const int swz  = l15 & 7;       // read-side XOR (matches source-side XOR)

    const int nbase = blockIdx.x * BN;
    const int kw    = wave * WKSLICE;

    const float*          wsrc = W + (size_t)nbase * K + kw;
    const unsigned short* xa0  = xbf + (size_t)l15 * K + kw + quad * 8;
    const unsigned short* xa1  = xa0 + (size_t)16 * K;

    float* wb0 = wbuf + wave * (2 * CHFL);   // this wave's 2-buffer ring

    f32x4 acc0 = {0.f, 0.f, 0.f, 0.f};
    f32x4 acc1 = {0.f, 0.f, 0.f, 0.f};

    // Stage chunk c of this wave's K-slice into buffer b (8 x 1KB DMAs).
    // Instruction i covers rows 2i,2i+1; LDS linear, global source carries
    // the XOR so that LDS slot s of row r holds global 16B-chunk (s^(r&7)).
#define STAGE(c, b) do {                                                      \
    _Pragma("unroll")                                                         \
    for (int i = 0; i < 8; ++i) {                                             \
        const int row_ = 2 * i + rp;                                          \
        const float* s_ = wsrc + (size_t)row_ * K + (c) * CK                  \
                          + ((slot ^ (row_ & 7)) << 2);                       \
        async_cp16(s_, wb0 + (b) * CHFL + i * 256);                           \
    }                                                                         \
} while (0)

    // Load this chunk's 8 A-fragments (global, L2-hot) into registers.
#define LOAD_A(c, A0, A1) do {                                                \
    _Pragma("unroll")                                                         \
    for (int s = 0; s < 4; ++s) {                                             \
        A0[s] = *(const bf16x8*)(xa0 + (c) * CK + s * 32);                    \
        A1[s] = *(const bf16x8*)(xa1 + (c) * CK + s * 32);                    \
    }                                                                         \
} while (0)

    // 4 k-steps of MFMA from LDS buffer b (swizzled ds_read_b128 pairs).
#define COMPUTE(b, A0, A1) do {                                               \
    const float* wb_ = wb0 + (b) * CHFL + l15 * CK;                           \
    _Pragma("unroll")                                                         \
    for (int s = 0; s < 4; ++s) {                                             \
        const int c0_ = s * 8 + quad * 2;                                     \
        f32x4 w0 = *(const f32x4*)(wb_ + ((c0_ ^ swz) << 2));                 \
        f32x4 w1 = *(const f32x4*)(wb_ + (((c0_ + 1) ^ swz) << 2));           \
        union { bf16x8 v; u32 u[4]; } bb;                                     \
        bb.u[0] = pk2bf(w0.x, w0.y);                                          \
        bb.u[1] = pk2bf(w0.z, w0.w);                                          \
        bb.u[2] = pk2bf(w1.x, w1.y);                                          \
        bb.u[3] = pk2bf(w1.z, w1.w);                                          \
        acc0 = __builtin_amdgcn_mfma_f32_16x16x32_bf16(A0[s], bb.v, acc0,     \
                                                       0, 0, 0);              \
        acc1 = __builtin_amdgcn_mfma_f32_16x16x32_bf16(A1[s], bb.v, acc1,     \
                                                       0, 0, 0);              \
    }                                                                         \
} while (0)

    bf16x8 a0A[4], a1A[4], a0B[4], a1B[4];

    // Prologue: queue = [W0(8), A0(8)]
    STAGE(0, 0);
    LOAD_A(0, a0A, a1A);

    #pragma unroll
    for (int c = 0; c < NCHUNK; ++c) {
        const int b = c & 1;
        if (c + 1 < NCHUNK) {
            STAGE(c + 1, b ^ 1);                 // queue += Wc+1(8)
            if ((c + 1) & 1) LOAD_A(c + 1, a0B, a1B);   // queue += Ac+1(8)
            else             LOAD_A(c + 1, a0A, a1A);
            // Oldest 16 of 32 = {Wc, Ac} -> landed. Wc+1/Ac+1 stay in flight.
            asm volatile("s_waitcnt vmcnt(16)" ::: "memory");
            __builtin_amdgcn_sched_barrier(0);   // pin: nothing hoists above
        } else {
            asm volatile("s_waitcnt vmcnt(0)" ::: "memory");
            __builtin_amdgcn_sched_barrier(0);
        }
        if (b) COMPUTE(b, a0B, a1B);
        else   COMPUTE(b, a0A, a1A);
    }

#undef STAGE
#undef LOAD_A
#undef COMPUTE

    // partials -> LDS (C/D layout: row = quad*4 + r, col = l15)
    #pragma unroll
    for (int r = 0; r < 4; ++r) {
        red[wave * 512 + (quad * 4 + r) * 16 + l15]      = acc0[r];
        red[wave * 512 + (16 + quad * 4 + r) * 16 + l15] = acc1[r];
    }
    __syncthreads();

    // 512 outputs, 256 threads x 2: sum 4 waves, add bias, store
    for (int e = tid; e < 512; e += 256) {
        float s = red[e] + red[512 + e] + red[1024 + e] + red[1536 + e];
        int m = e >> 4, n = e & 15;
        out[(size_t)m * N + nbase + n] = s + bias[nbase + n];
    }
}

extern "C" void kernel_launch(void* const* d_in, const int* in_sizes, int n_in,
                              void* d_out, int out_size, void* d_ws, size_t ws_size,
                              hipStream_t stream) {
    const float* x    = (const float*)d_in[0];
    const float* W    = (const float*)d_in[1];
    const float* bias = (const float*)d_in[2];
    float* out        = (float*)d_out;
    unsigned short* xbf = (unsigned short*)d_ws;   // 256 KB

    cvt_kernel<<<(M * K / 4) / 256, 256, 0, stream>>>(x, xbf);
    gemm_kernel<<<N / BN, 256, 0, stream>>>(W, xbf, bias, out);
}